// Round 13
// baseline (142.072 us; speedup 1.0000x reference)
//
#include <hip/hip_runtime.h>
#include <math.h>

#define NPTS   8192
#define BITS   64
#define NCLS   101
#define TILE   128
#define NT     (NPTS / TILE)            // 64
#define NPAIRS (NT * (NT + 1) / 2)      // 2080
#define SCALE  0.84932184f              // sqrt(0.5*log2 e): acc = t = theta*log2(e)
#define LN2    0.6931471805599453
#define SCH_BITS 1064872494             // (127<<23) - 0.0573*2^23 (mean-zero Schraudolph)

// ws: double accum[4] {sp_all, sp_same, t_same, cls} @0; unsigned counter @32.
// Elected block resets accum to 0.0 each call; counter free-runs (modular elect).

typedef short    bf16x8   __attribute__((ext_vector_type(8)));
typedef unsigned short ushort8v __attribute__((ext_vector_type(8)));
typedef float    f32x16   __attribute__((ext_vector_type(16)));

__device__ __forceinline__ unsigned short f2bf(float f) {
    unsigned int u = __float_as_uint(f);
    u += 0x7FFFu + ((u >> 16) & 1u);     // RNE (inputs finite)
    return (unsigned short)(u >> 16);
}
__device__ __forceinline__ float flog2(float x) {
    float r; asm("v_log_f32 %0, %1" : "=v"(r) : "v"(x)); return r;
}
__device__ __forceinline__ float exp2_fast(float v) {   // |v| < ~90, v <= 0
    int ib = (int)(v * 8388608.0f);
    return __int_as_float(ib + SCH_BITS);
}
__device__ __forceinline__ void tile_map(int p, int& ti, int& tj) {
    float disc = (2.0f * NT + 1.0f) * (2.0f * NT + 1.0f) - 8.0f * (float)p;
    ti = (int)(((2.0f * NT + 1.0f) - sqrtf(disc)) * 0.5f);
    if (ti < 0) ti = 0;
    if (ti >= NT) ti = NT - 1;
    while (ti > 0 && (ti * NT - ti * (ti - 1) / 2) > p) ti--;
    while ((ti + 1) * NT - (ti + 1) * ti / 2 <= p) ti++;
    tj = ti + (p - (ti * NT - ti * (ti - 1) / 2));
}

// ---------------------------------------------------------------------------
// Single fused kernel: hash tile + cls rows + last-block finalize.
// ---------------------------------------------------------------------------
__global__ __launch_bounds__(256, 3) void fused_kernel(const float* __restrict__ H,
                                                       const float* __restrict__ X,
                                                       const int* __restrict__ tgt,
                                                       double* __restrict__ acc,
                                                       unsigned* __restrict__ counter,
                                                       float* __restrict__ out) {
    __shared__ unsigned short As[TILE * BITS];
    __shared__ unsigned short Bs[TILE * BITS];
    __shared__ int tI[TILE];
    __shared__ int tJ[TILE];
    __shared__ float red[16];
    __shared__ int elect_s;

    const int tid = threadIdx.x;
    const int p = blockIdx.x;
    int ti, tj; tile_map(p, ti, tj);
    const int i0 = ti * TILE, j0 = tj * TILE;
    const bool diag = (ti == tj);
    const int lane = tid & 63, wave = tid >> 6;

    if (tid < TILE) { tI[tid] = tgt[i0 + tid]; tJ[tid] = tgt[j0 + tid]; }

    // ---- staging phase 1: issue ALL 16 global float4 loads (deep MLP) ----
    float4 buf0[8], buf1[8];
#pragma unroll
    for (int it = 0; it < 8; ++it) {
        const int idx  = tid + it * 256;
        const int half = idx >> 10;
        const int lid  = idx & 1023;
        const int row  = lid >> 3;
        const int c    = lid & 7;
        const float* src = H + (size_t)((half ? j0 : i0) + row) * BITS + c * 8;
        buf0[it] = *(const float4*)src;
        buf1[it] = *(const float4*)(src + 4);
    }

    // ---- cls loads hoisted: latency hides under convert/MFMA ----
    const int crow = p * 4 + wave;
    float cx1 = -INFINITY, cx2 = -INFINITY, cxt = 0.f;
    if (crow < NPTS) {
        const float* x = X + (size_t)crow * NCLS;
        cx1 = x[lane];
        cx2 = (lane + 64 < NCLS) ? x[lane + 64] : -INFINITY;
        cxt = x[tgt[crow]];
    }

    // ---- staging phase 2: convert + swizzled LDS write ----
#pragma unroll
    for (int it = 0; it < 8; ++it) {
        const int idx  = tid + it * 256;
        const int half = idx >> 10;
        const int lid  = idx & 1023;
        const int row  = lid >> 3;
        const int c    = lid & 7;
        ushort8v v;
        v[0] = f2bf(buf0[it].x * SCALE); v[1] = f2bf(buf0[it].y * SCALE);
        v[2] = f2bf(buf0[it].z * SCALE); v[3] = f2bf(buf0[it].w * SCALE);
        v[4] = f2bf(buf1[it].x * SCALE); v[5] = f2bf(buf1[it].y * SCALE);
        v[6] = f2bf(buf1[it].z * SCALE); v[7] = f2bf(buf1[it].w * SCALE);
        unsigned short* dst = half ? Bs : As;
        *(ushort8v*)&dst[row * BITS + ((c ^ (row & 7)) * 8)] = v;
    }
    __syncthreads();

    const int wr = wave >> 1, wc = wave & 1;
    const int lrow = lane & 31, hi = lane >> 5;

    f32x16 c00, c01, c10, c11;
#pragma unroll
    for (int e = 0; e < 16; ++e) { c00[e] = 0.f; c01[e] = 0.f; c10[e] = 0.f; c11[e] = 0.f; }

    auto ldfrag = [](const unsigned short* S, int row, int chunk) -> bf16x8 {
        ushort8v r = *(const ushort8v*)&S[row * BITS + ((chunk ^ (row & 7)) * 8)];
        return __builtin_bit_cast(bf16x8, r);
    };

#pragma unroll
    for (int ks = 0; ks < 4; ++ks) {
        const int ch = ks * 2 + hi;
        bf16x8 a0 = ldfrag(As, wr * 64 +      lrow, ch);
        bf16x8 a1 = ldfrag(As, wr * 64 + 32 + lrow, ch);
        bf16x8 b0 = ldfrag(Bs, wc * 64 +      lrow, ch);
        bf16x8 b1 = ldfrag(Bs, wc * 64 + 32 + lrow, ch);
        c00 = __builtin_amdgcn_mfma_f32_32x32x16_bf16(a0, b0, c00, 0, 0, 0);
        c01 = __builtin_amdgcn_mfma_f32_32x32x16_bf16(a0, b1, c01, 0, 0, 0);
        c10 = __builtin_amdgcn_mfma_f32_32x32x16_bf16(a1, b0, c10, 0, 0, 0);
        c11 = __builtin_amdgcn_mfma_f32_32x32x16_bf16(a1, b1, c11, 0, 0, 0);
    }

    float prod_all = 1.f, prod_same = 1.f;
    float s_relu = 0.f, s_relu_s = 0.f, t_sum_s = 0.f;

    if (!diag) {
#pragma unroll
        for (int it = 0; it < 2; ++it) {
            int trow[16];
#pragma unroll
            for (int r = 0; r < 16; ++r)
                trow[r] = tI[wr * 64 + it * 32 + (r & 3) + 8 * (r >> 2) + 4 * hi];
#pragma unroll
            for (int jt = 0; jt < 2; ++jt) {
                const int tc = tJ[wc * 64 + jt * 32 + lrow];
                const f32x16& C = it ? (jt ? c11 : c10) : (jt ? c01 : c00);
#pragma unroll
                for (int r = 0; r < 16; ++r) {
                    float t = C[r];                           // theta*log2e
                    float u = exp2_fast(fminf(t, 0.f - t));   // 2^{-|t|} (no clamp)
                    float w = 1.0f + u;
                    float mf = (trow[r] == tc) ? 1.0f : 0.0f;
                    prod_all  *= w;
                    prod_same *= fmaf(mf, u, 1.0f);
                    float rl = fmaxf(t, 0.f);
                    s_relu   += rl;
                    s_relu_s  = fmaf(mf, rl, s_relu_s);
                    t_sum_s   = fmaf(mf, t,  t_sum_s);
                }
            }
        }
    } else {
#pragma unroll
        for (int it = 0; it < 2; ++it) {
            int trow[16], lrr[16];
#pragma unroll
            for (int r = 0; r < 16; ++r) {
                lrr[r] = wr * 64 + it * 32 + (r & 3) + 8 * (r >> 2) + 4 * hi;
                trow[r] = tI[lrr[r]];
            }
#pragma unroll
            for (int jt = 0; jt < 2; ++jt) {
                const int lc = wc * 64 + jt * 32 + lrow;
                const int tc = tJ[lc];
                const f32x16& C = it ? (jt ? c11 : c10) : (jt ? c01 : c00);
#pragma unroll
                for (int r = 0; r < 16; ++r) {
                    float t = C[r];
                    float u = exp2_fast(fminf(t, 0.f - t));
                    float w = 1.0f + u;
                    bool  vd = lc > lrr[r];
                    float vf = vd ? 1.0f : 0.0f;
                    float mf = (vd && trow[r] == tc) ? 1.0f : 0.0f;
                    prod_all  *= fmaf(vf, u, 1.0f);
                    prod_same *= fmaf(mf, u, 1.0f);
                    float rl = fmaxf(t, 0.f);
                    s_relu    = fmaf(vf, rl, s_relu);
                    s_relu_s  = fmaf(mf, rl, s_relu_s);
                    t_sum_s   = fmaf(mf, t,  t_sum_s);
                    (void)w;
                }
            }
        }
    }

    float s_all  = s_relu   + flog2(prod_all);    // softplus/ln2 totals
    float s_same = s_relu_s + flog2(prod_same);
    float t_same = t_sum_s;

#pragma unroll
    for (int d = 32; d > 0; d >>= 1) {
        s_all  += __shfl_xor(s_all,  d, 64);
        s_same += __shfl_xor(s_same, d, 64);
        t_same += __shfl_xor(t_same, d, 64);
    }
    if (lane == 0) { red[wave] = s_all; red[4 + wave] = s_same; red[8 + wave] = t_same; }

    {   // cls softmax on preloaded registers
        float nll = 0.f;
        if (crow < NPTS) {
            float m = fmaxf(cx1, cx2);
#pragma unroll
            for (int d = 32; d > 0; d >>= 1) m = fmaxf(m, __shfl_xor(m, d, 64));
            float e = __expf(cx1 - m) + ((lane + 64 < NCLS) ? __expf(cx2 - m) : 0.f);
#pragma unroll
            for (int d = 32; d > 0; d >>= 1) e += __shfl_xor(e, d, 64);
            if (lane == 0) nll = m + __logf(e) - cxt;
        }
        if (lane == 0) red[12 + wave] = nll;
    }
    __syncthreads();

    if (tid == 0) {
        double va = (double)red[0]  + (double)red[1]  + (double)red[2]  + (double)red[3];
        double vs = (double)red[4]  + (double)red[5]  + (double)red[6]  + (double)red[7];
        double vt = (double)red[8]  + (double)red[9]  + (double)red[10] + (double)red[11];
        double vc = (double)red[12] + (double)red[13] + (double)red[14] + (double)red[15];
        atomicAdd(&acc[0], va);
        atomicAdd(&acc[1], vs);
        atomicAdd(&acc[2], vt);
        atomicAdd(&acc[3], vc);
        __threadfence();
        unsigned old = atomicAdd(counter, 1u);
        elect_s = ((old + 1u) % (unsigned)NPAIRS == 0u) ? 1 : 0;
    }
    __syncthreads();

    if (elect_s) {
        // ---- last block: finalize ----
        int* hist = (int*)As;                      // reuse LDS
        for (int i = tid; i < NCLS; i += 256) hist[i] = 0;
        __syncthreads();
        for (int i = tid; i < NPTS; i += 256) atomicAdd(&hist[tgt[i]], 1);
        __syncthreads();

        if (tid == 0) {
            __threadfence();                       // acquire side
            const double A_all  = atomicAdd(&acc[0], 0.0);
            const double A_same = atomicAdd(&acc[1], 0.0);
            const double A_t    = atomicAdd(&acc[2], 0.0);
            const double A_cls  = atomicAdd(&acc[3], 0.0);

            double n_pos = 0.0;
            for (int k = 0; k < NCLS; ++k) {
                double cc = (double)hist[k];
                n_pos += cc * cc;
            }
            const double Nd = (double)NPTS;
            double S1 = n_pos - Nd;
            double S0 = Nd * Nd - n_pos;
            if (S0 == 0.0) S0 = 1.0;
            if (S1 == 0.0) S1 = 1.0;
            const double S = S0 + S1;
            const double sum_lower =
                ((S / S0) * (A_all - A_same) + (S / S1) * (A_same - A_t)) * LN2;
            const double count = Nd * (Nd - 1.0) * 0.5;
            const double hash_loss = sum_lower / count;
            const double cls_loss  = A_cls / Nd;
            const double loss = 1.0 * cls_loss + 0.01 * hash_loss;
            out[0] = (float)hash_loss;
            out[1] = (float)cls_loss;
            out[2] = (float)loss;

            // reset accumulators for the next call (coherent exchange)
            atomicExch((unsigned long long*)&acc[0], 0ull);
            atomicExch((unsigned long long*)&acc[1], 0ull);
            atomicExch((unsigned long long*)&acc[2], 0ull);
            atomicExch((unsigned long long*)&acc[3], 0ull);
        }
    }
}

// ---------------------------------------------------------------------------
extern "C" void kernel_launch(void* const* d_in, const int* in_sizes, int n_in,
                              void* d_out, int out_size, void* d_ws, size_t ws_size,
                              hipStream_t stream) {
    const float* H   = (const float*)d_in[0];
    const float* X   = (const float*)d_in[1];
    const int*   tgt = (const int*)d_in[2];
    float* out = (float*)d_out;
    double* acc = (double*)d_ws;
    unsigned* counter = (unsigned*)((char*)d_ws + 32);

    fused_kernel<<<NPAIRS, 256, 0, stream>>>(H, X, tgt, acc, counter, out);
}

// Round 14
// 127.732 us; speedup vs baseline: 1.1123x; 1.1123x over previous
//
#include <hip/hip_runtime.h>
#include <math.h>

#define NPTS   8192
#define BITS   64
#define NCLS   101
#define TILE   128
#define NT     (NPTS / TILE)            // 64
#define NPAIRS (NT * (NT + 1) / 2)      // 2080
#define SCALE  0.84932184f              // sqrt(0.5*log2 e): acc = t = theta*log2(e)
#define LN2    0.6931471805599453
#define SCH_BITS 1064872494             // (127<<23) - 0.0573*2^23 (mean-zero Schraudolph)

// ws layout: double part[NPAIRS*5] @0  {sp_all, sp_same, t_same, cnt_same, cls};
//            unsigned counter @ NPAIRS*5*8. Partials fully rewritten per call
//            before being read; counter free-runs (modular election).

typedef short    bf16x8   __attribute__((ext_vector_type(8)));
typedef unsigned short ushort8v __attribute__((ext_vector_type(8)));
typedef float    f32x16   __attribute__((ext_vector_type(16)));

__device__ __forceinline__ unsigned short f2bf(float f) {
    unsigned int u = __float_as_uint(f);
    u += 0x7FFFu + ((u >> 16) & 1u);     // RNE (inputs finite)
    return (unsigned short)(u >> 16);
}
__device__ __forceinline__ float flog2(float x) {
    float r; asm("v_log_f32 %0, %1" : "=v"(r) : "v"(x)); return r;
}
__device__ __forceinline__ float exp2_fast(float v) {   // v <= 0, |v| < ~90
    int ib = (int)(v * 8388608.0f);
    return __int_as_float(ib + SCH_BITS);
}
__device__ __forceinline__ void tile_map(int p, int& ti, int& tj) {
    float disc = (2.0f * NT + 1.0f) * (2.0f * NT + 1.0f) - 8.0f * (float)p;
    ti = (int)(((2.0f * NT + 1.0f) - sqrtf(disc)) * 0.5f);
    if (ti < 0) ti = 0;
    if (ti >= NT) ti = NT - 1;
    while (ti > 0 && (ti * NT - ti * (ti - 1) / 2) > p) ti--;
    while ((ti + 1) * NT - (ti + 1) * ti / 2 <= p) ti++;
    tj = ti + (p - (ti * NT - ti * (ti - 1) / 2));
}

// ---------------------------------------------------------------------------
// Single fused kernel: hash tile + cls rows; per-block partial slots (release
// stores, NO fp atomics); native u32 counter; elected last block reduces.
// ---------------------------------------------------------------------------
__global__ __launch_bounds__(256, 3) void fused_kernel(const float* __restrict__ H,
                                                       const float* __restrict__ X,
                                                       const int* __restrict__ tgt,
                                                       double* __restrict__ part,
                                                       unsigned* __restrict__ counter,
                                                       float* __restrict__ out) {
    __shared__ unsigned short As[TILE * BITS];
    __shared__ unsigned short Bs[TILE * BITS];
    __shared__ int tI[TILE];
    __shared__ int tJ[TILE];
    __shared__ float red[20];
    __shared__ int elect_s;

    const int tid = threadIdx.x;
    const int p = blockIdx.x;
    int ti, tj; tile_map(p, ti, tj);
    const int i0 = ti * TILE, j0 = tj * TILE;
    const bool diag = (ti == tj);
    const int lane = tid & 63, wave = tid >> 6;

    if (tid < TILE) { tI[tid] = tgt[i0 + tid]; tJ[tid] = tgt[j0 + tid]; }

    // ---- staging phase 1: issue ALL 16 global float4 loads (deep MLP) ----
    float4 buf0[8], buf1[8];
#pragma unroll
    for (int it = 0; it < 8; ++it) {
        const int idx  = tid + it * 256;
        const int half = idx >> 10;
        const int lid  = idx & 1023;
        const int row  = lid >> 3;
        const int c    = lid & 7;
        const float* src = H + (size_t)((half ? j0 : i0) + row) * BITS + c * 8;
        buf0[it] = *(const float4*)src;
        buf1[it] = *(const float4*)(src + 4);
    }

    // ---- cls loads hoisted: latency hides under convert/MFMA ----
    const int crow = p * 4 + wave;
    float cx1 = -INFINITY, cx2 = -INFINITY, cxt = 0.f;
    if (crow < NPTS) {
        const float* x = X + (size_t)crow * NCLS;
        cx1 = x[lane];
        cx2 = (lane + 64 < NCLS) ? x[lane + 64] : -INFINITY;
        cxt = x[tgt[crow]];
    }

    // ---- staging phase 2: convert + swizzled LDS write ----
#pragma unroll
    for (int it = 0; it < 8; ++it) {
        const int idx  = tid + it * 256;
        const int half = idx >> 10;
        const int lid  = idx & 1023;
        const int row  = lid >> 3;
        const int c    = lid & 7;
        ushort8v v;
        v[0] = f2bf(buf0[it].x * SCALE); v[1] = f2bf(buf0[it].y * SCALE);
        v[2] = f2bf(buf0[it].z * SCALE); v[3] = f2bf(buf0[it].w * SCALE);
        v[4] = f2bf(buf1[it].x * SCALE); v[5] = f2bf(buf1[it].y * SCALE);
        v[6] = f2bf(buf1[it].z * SCALE); v[7] = f2bf(buf1[it].w * SCALE);
        unsigned short* dst = half ? Bs : As;
        *(ushort8v*)&dst[row * BITS + ((c ^ (row & 7)) * 8)] = v;
    }
    __syncthreads();

    const int wr = wave >> 1, wc = wave & 1;
    const int lrow = lane & 31, hi = lane >> 5;

    f32x16 c00, c01, c10, c11;
#pragma unroll
    for (int e = 0; e < 16; ++e) { c00[e] = 0.f; c01[e] = 0.f; c10[e] = 0.f; c11[e] = 0.f; }

    auto ldfrag = [](const unsigned short* S, int row, int chunk) -> bf16x8 {
        ushort8v r = *(const ushort8v*)&S[row * BITS + ((chunk ^ (row & 7)) * 8)];
        return __builtin_bit_cast(bf16x8, r);
    };

#pragma unroll
    for (int ks = 0; ks < 4; ++ks) {
        const int ch = ks * 2 + hi;
        bf16x8 a0 = ldfrag(As, wr * 64 +      lrow, ch);
        bf16x8 a1 = ldfrag(As, wr * 64 + 32 + lrow, ch);
        bf16x8 b0 = ldfrag(Bs, wc * 64 +      lrow, ch);
        bf16x8 b1 = ldfrag(Bs, wc * 64 + 32 + lrow, ch);
        c00 = __builtin_amdgcn_mfma_f32_32x32x16_bf16(a0, b0, c00, 0, 0, 0);
        c01 = __builtin_amdgcn_mfma_f32_32x32x16_bf16(a0, b1, c01, 0, 0, 0);
        c10 = __builtin_amdgcn_mfma_f32_32x32x16_bf16(a1, b0, c10, 0, 0, 0);
        c11 = __builtin_amdgcn_mfma_f32_32x32x16_bf16(a1, b1, c11, 0, 0, 0);
    }

    float prod_all = 1.f, prod_same = 1.f;
    float s_relu = 0.f, s_relu_s = 0.f, t_sum_s = 0.f, cnt_s = 0.f;

    if (!diag) {
#pragma unroll
        for (int it = 0; it < 2; ++it) {
            int trow[16];
#pragma unroll
            for (int r = 0; r < 16; ++r)
                trow[r] = tI[wr * 64 + it * 32 + (r & 3) + 8 * (r >> 2) + 4 * hi];
#pragma unroll
            for (int jt = 0; jt < 2; ++jt) {
                const int tc = tJ[wc * 64 + jt * 32 + lrow];
                const f32x16& C = it ? (jt ? c11 : c10) : (jt ? c01 : c00);
#pragma unroll
                for (int r = 0; r < 16; ++r) {
                    float t = C[r];                           // theta*log2e
                    float u = exp2_fast(fminf(t, 0.f - t));   // 2^{-|t|}
                    float mf = (trow[r] == tc) ? 1.0f : 0.0f;
                    prod_all  *= 1.0f + u;
                    prod_same *= fmaf(mf, u, 1.0f);
                    float rl = fmaxf(t, 0.f);
                    s_relu   += rl;
                    s_relu_s  = fmaf(mf, rl, s_relu_s);
                    t_sum_s   = fmaf(mf, t,  t_sum_s);
                    cnt_s    += mf;
                }
            }
        }
    } else {
#pragma unroll
        for (int it = 0; it < 2; ++it) {
            int trow[16], lrr[16];
#pragma unroll
            for (int r = 0; r < 16; ++r) {
                lrr[r] = wr * 64 + it * 32 + (r & 3) + 8 * (r >> 2) + 4 * hi;
                trow[r] = tI[lrr[r]];
            }
#pragma unroll
            for (int jt = 0; jt < 2; ++jt) {
                const int lc = wc * 64 + jt * 32 + lrow;
                const int tc = tJ[lc];
                const f32x16& C = it ? (jt ? c11 : c10) : (jt ? c01 : c00);
#pragma unroll
                for (int r = 0; r < 16; ++r) {
                    float t = C[r];
                    float u = exp2_fast(fminf(t, 0.f - t));
                    bool  vd = lc > lrr[r];
                    float vf = vd ? 1.0f : 0.0f;
                    float mf = (vd && trow[r] == tc) ? 1.0f : 0.0f;
                    prod_all  *= fmaf(vf, u, 1.0f);
                    prod_same *= fmaf(mf, u, 1.0f);
                    float rl = fmaxf(t, 0.f);
                    s_relu    = fmaf(vf, rl, s_relu);
                    s_relu_s  = fmaf(mf, rl, s_relu_s);
                    t_sum_s   = fmaf(mf, t,  t_sum_s);
                    cnt_s    += mf;
                }
            }
        }
    }

    float s_all  = s_relu   + flog2(prod_all);    // softplus/ln2 totals
    float s_same = s_relu_s + flog2(prod_same);
    float t_same = t_sum_s;

#pragma unroll
    for (int d = 32; d > 0; d >>= 1) {
        s_all  += __shfl_xor(s_all,  d, 64);
        s_same += __shfl_xor(s_same, d, 64);
        t_same += __shfl_xor(t_same, d, 64);
        cnt_s  += __shfl_xor(cnt_s,  d, 64);
    }
    if (lane == 0) {
        red[wave] = s_all; red[4 + wave] = s_same;
        red[8 + wave] = t_same; red[12 + wave] = cnt_s;
    }

    {   // cls softmax on preloaded registers
        float nll = 0.f;
        if (crow < NPTS) {
            float m = fmaxf(cx1, cx2);
#pragma unroll
            for (int d = 32; d > 0; d >>= 1) m = fmaxf(m, __shfl_xor(m, d, 64));
            float e = __expf(cx1 - m) + ((lane + 64 < NCLS) ? __expf(cx2 - m) : 0.f);
#pragma unroll
            for (int d = 32; d > 0; d >>= 1) e += __shfl_xor(e, d, 64);
            if (lane == 0) nll = m + __logf(e) - cxt;
        }
        if (lane == 0) red[16 + wave] = nll;
    }
    __syncthreads();

    if (tid == 0) {
        double* q = part + (size_t)p * 5;
        double va = (double)red[0]  + (double)red[1]  + (double)red[2]  + (double)red[3];
        double vs = (double)red[4]  + (double)red[5]  + (double)red[6]  + (double)red[7];
        double vt = (double)red[8]  + (double)red[9]  + (double)red[10] + (double)red[11];
        double vn = (double)red[12] + (double)red[13] + (double)red[14] + (double)red[15];
        double vc = (double)red[16] + (double)red[17] + (double)red[18] + (double)red[19];
        __hip_atomic_store(&q[0], va, __ATOMIC_RELEASE, __HIP_MEMORY_SCOPE_AGENT);
        __hip_atomic_store(&q[1], vs, __ATOMIC_RELEASE, __HIP_MEMORY_SCOPE_AGENT);
        __hip_atomic_store(&q[2], vt, __ATOMIC_RELEASE, __HIP_MEMORY_SCOPE_AGENT);
        __hip_atomic_store(&q[3], vn, __ATOMIC_RELEASE, __HIP_MEMORY_SCOPE_AGENT);
        __hip_atomic_store(&q[4], vc, __ATOMIC_RELEASE, __HIP_MEMORY_SCOPE_AGENT);
        unsigned old = __hip_atomic_fetch_add(counter, 1u, __ATOMIC_ACQ_REL,
                                              __HIP_MEMORY_SCOPE_AGENT);
        elect_s = ((old + 1u) % (unsigned)NPAIRS == 0u) ? 1 : 0;
    }
    __syncthreads();

    if (elect_s) {
        __threadfence();
        double a0 = 0.0, a1 = 0.0, a2 = 0.0, a3 = 0.0, a4 = 0.0;
        for (int i = tid; i < NPAIRS; i += 256) {
            const double* q = part + (size_t)i * 5;
            a0 += __hip_atomic_load(&q[0], __ATOMIC_RELAXED, __HIP_MEMORY_SCOPE_AGENT);
            a1 += __hip_atomic_load(&q[1], __ATOMIC_RELAXED, __HIP_MEMORY_SCOPE_AGENT);
            a2 += __hip_atomic_load(&q[2], __ATOMIC_RELAXED, __HIP_MEMORY_SCOPE_AGENT);
            a3 += __hip_atomic_load(&q[3], __ATOMIC_RELAXED, __HIP_MEMORY_SCOPE_AGENT);
            a4 += __hip_atomic_load(&q[4], __ATOMIC_RELAXED, __HIP_MEMORY_SCOPE_AGENT);
        }
        double* dr = (double*)As;            // reuse 32KB LDS (As+Bs contiguous? use As only: 2048 doubles)
        dr[tid] = a0; dr[256 + tid] = a1; dr[512 + tid] = a2;
        dr[768 + tid] = a3; dr[1024 + tid] = a4;
        __syncthreads();
        for (int sd = 128; sd > 0; sd >>= 1) {
            if (tid < sd) {
                dr[tid]        += dr[tid + sd];
                dr[256 + tid]  += dr[256 + tid + sd];
                dr[512 + tid]  += dr[512 + tid + sd];
                dr[768 + tid]  += dr[768 + tid + sd];
                dr[1024 + tid] += dr[1024 + tid + sd];
            }
            __syncthreads();
        }
        if (tid == 0) {
            const double A_all = dr[0], A_same = dr[256], A_t = dr[512];
            const double A_cnt = dr[768], A_cls = dr[1024];
            const double Nd = (double)NPTS;
            double S1 = 2.0 * A_cnt;                 // n_pos - N
            double S0 = Nd * Nd - (S1 + Nd);
            if (S0 == 0.0) S0 = 1.0;
            if (S1 == 0.0) S1 = 1.0;
            const double S = S0 + S1;
            const double sum_lower =
                ((S / S0) * (A_all - A_same) + (S / S1) * (A_same - A_t)) * LN2;
            const double count = Nd * (Nd - 1.0) * 0.5;
            const double hash_loss = sum_lower / count;
            const double cls_loss  = A_cls / Nd;
            const double loss = 1.0 * cls_loss + 0.01 * hash_loss;
            out[0] = (float)hash_loss;
            out[1] = (float)cls_loss;
            out[2] = (float)loss;
        }
    }
}

// ---------------------------------------------------------------------------
extern "C" void kernel_launch(void* const* d_in, const int* in_sizes, int n_in,
                              void* d_out, int out_size, void* d_ws, size_t ws_size,
                              hipStream_t stream) {
    const float* H   = (const float*)d_in[0];
    const float* X   = (const float*)d_in[1];
    const int*   tgt = (const int*)d_in[2];
    float* out = (float*)d_out;
    double* part = (double*)d_ws;
    unsigned* counter = (unsigned*)((char*)d_ws + (size_t)NPAIRS * 5 * 8);

    fused_kernel<<<NPAIRS, 256, 0, stream>>>(H, X, tgt, part, counter, out);
}

// Round 15
// 35.820 us; speedup vs baseline: 3.9662x; 3.5659x over previous
//
#include <hip/hip_runtime.h>
#include <math.h>

#define NPTS   8192
#define BITS   64
#define NCLS   101
#define TILE   128
#define NT     (NPTS / TILE)            // 64
#define NPAIRS (NT * (NT + 1) / 2)      // 2080
#define WS_CLS (3 * NPAIRS)
#define SCALE  0.84932184f              // sqrt(0.5*log2 e): acc = t = theta*log2(e)
#define LN2    0.6931471805599453
#define SCH_BITS 1064872494             // (127<<23) - 0.0573*2^23 (mean-zero Schraudolph)

// ws doubles: [0,N) sp_all(log2 units) | [N,2N) sp_same | [2N,3N) t_same | [3N,4N) cls

typedef short    bf16x8   __attribute__((ext_vector_type(8)));
typedef unsigned short ushort8v __attribute__((ext_vector_type(8)));
typedef float    f32x16  __attribute__((ext_vector_type(16)));
typedef float    f32x2   __attribute__((ext_vector_type(2)));

__device__ __forceinline__ float flog2(float x) {
    float r; asm("v_log_f32 %0, %1" : "=v"(r) : "v"(x)); return r;
}
// HW packed fp32->bf16 convert (RNE), 2 elems / instruction.
__device__ __forceinline__ unsigned cvt_pk_bf16(float lo, float hi) {
    unsigned r;
    asm("v_cvt_pk_bf16_f32 %0, %1, %2" : "=v"(r) : "v"(lo), "v"(hi));
    return r;
}
__device__ __forceinline__ void tile_map(int p, int& ti, int& tj) {
    float disc = (2.0f * NT + 1.0f) * (2.0f * NT + 1.0f) - 8.0f * (float)p;
    ti = (int)(((2.0f * NT + 1.0f) - sqrtf(disc)) * 0.5f);
    if (ti < 0) ti = 0;
    if (ti >= NT) ti = NT - 1;
    while (ti > 0 && (ti * NT - ti * (ti - 1) / 2) > p) ti--;
    while ((ti + 1) * NT - (ti + 1) * ti / 2 <= p) ti++;
    tj = ti + (p - (ti * NT - ti * (ti - 1) / 2));
}

// ---------------------------------------------------------------------------
// Fused hash tile + cls rows (R12 structure). Staging via v_cvt_pk_bf16_f32;
// epilogue in packed-fp32 pairs (v_pk_* on CDNA4), Schraudolph log-of-product.
// ---------------------------------------------------------------------------
__global__ __launch_bounds__(256, 3) void hash_cls_kernel(const float* __restrict__ H,
                                                          const float* __restrict__ X,
                                                          const int* __restrict__ tgt,
                                                          double* __restrict__ ws) {
    __shared__ unsigned short As[TILE * BITS];
    __shared__ unsigned short Bs[TILE * BITS];
    __shared__ int tI[TILE];
    __shared__ int tJ[TILE];
    __shared__ float red[16];

    const int tid = threadIdx.x;
    const int p = blockIdx.x;
    int ti, tj; tile_map(p, ti, tj);
    const int i0 = ti * TILE, j0 = tj * TILE;
    const bool diag = (ti == tj);
    const int lane = tid & 63, wave = tid >> 6;

    if (tid < TILE) { tI[tid] = tgt[i0 + tid]; tJ[tid] = tgt[j0 + tid]; }

    // ---- staging phase 1: issue ALL 16 global float4 loads (deep MLP) ----
    float4 buf0[8], buf1[8];
#pragma unroll
    for (int it = 0; it < 8; ++it) {
        const int idx  = tid + it * 256;
        const int half = idx >> 10;
        const int lid  = idx & 1023;
        const int row  = lid >> 3;
        const int c    = lid & 7;
        const float* src = H + (size_t)((half ? j0 : i0) + row) * BITS + c * 8;
        buf0[it] = *(const float4*)src;
        buf1[it] = *(const float4*)(src + 4);
    }

    // ---- cls loads hoisted: latency hides under convert/MFMA ----
    const int crow = p * 4 + wave;
    float cx1 = -INFINITY, cx2 = -INFINITY, cxt = 0.f;
    if (crow < NPTS) {
        const float* x = X + (size_t)crow * NCLS;
        cx1 = x[lane];
        cx2 = (lane + 64 < NCLS) ? x[lane + 64] : -INFINITY;
        cxt = x[tgt[crow]];
    }

    // ---- staging phase 2: HW packed convert + swizzled LDS write ----
#pragma unroll
    for (int it = 0; it < 8; ++it) {
        const int idx  = tid + it * 256;
        const int half = idx >> 10;
        const int lid  = idx & 1023;
        const int row  = lid >> 3;
        const int c    = lid & 7;
        uint4 v;
        v.x = cvt_pk_bf16(buf0[it].x * SCALE, buf0[it].y * SCALE);
        v.y = cvt_pk_bf16(buf0[it].z * SCALE, buf0[it].w * SCALE);
        v.z = cvt_pk_bf16(buf1[it].x * SCALE, buf1[it].y * SCALE);
        v.w = cvt_pk_bf16(buf1[it].z * SCALE, buf1[it].w * SCALE);
        unsigned short* dst = half ? Bs : As;
        *(uint4*)&dst[row * BITS + ((c ^ (row & 7)) * 8)] = v;
    }
    __syncthreads();

    const int wr = wave >> 1, wc = wave & 1;
    const int lrow = lane & 31, hi = lane >> 5;

    f32x16 c00, c01, c10, c11;
#pragma unroll
    for (int e = 0; e < 16; ++e) { c00[e] = 0.f; c01[e] = 0.f; c10[e] = 0.f; c11[e] = 0.f; }

    auto ldfrag = [](const unsigned short* S, int row, int chunk) -> bf16x8 {
        ushort8v r = *(const ushort8v*)&S[row * BITS + ((chunk ^ (row & 7)) * 8)];
        return __builtin_bit_cast(bf16x8, r);
    };

#pragma unroll
    for (int ks = 0; ks < 4; ++ks) {
        const int ch = ks * 2 + hi;
        bf16x8 a0 = ldfrag(As, wr * 64 +      lrow, ch);
        bf16x8 a1 = ldfrag(As, wr * 64 + 32 + lrow, ch);
        bf16x8 b0 = ldfrag(Bs, wc * 64 +      lrow, ch);
        bf16x8 b1 = ldfrag(Bs, wc * 64 + 32 + lrow, ch);
        c00 = __builtin_amdgcn_mfma_f32_32x32x16_bf16(a0, b0, c00, 0, 0, 0);
        c01 = __builtin_amdgcn_mfma_f32_32x32x16_bf16(a0, b1, c01, 0, 0, 0);
        c10 = __builtin_amdgcn_mfma_f32_32x32x16_bf16(a1, b0, c10, 0, 0, 0);
        c11 = __builtin_amdgcn_mfma_f32_32x32x16_bf16(a1, b1, c11, 0, 0, 0);
    }

    // packed-pair epilogue state
    f32x2 prodA = {1.f, 1.f}, prodS = {1.f, 1.f};
    f32x2 sRelu = {0.f, 0.f}, sReluS = {0.f, 0.f}, tSum = {0.f, 0.f};

    if (!diag) {
#pragma unroll
        for (int it = 0; it < 2; ++it) {
            int trow[16];
#pragma unroll
            for (int r = 0; r < 16; ++r)
                trow[r] = tI[wr * 64 + it * 32 + (r & 3) + 8 * (r >> 2) + 4 * hi];
#pragma unroll
            for (int jt = 0; jt < 2; ++jt) {
                const int tc = tJ[wc * 64 + jt * 32 + lrow];
                const f32x16& C = it ? (jt ? c11 : c10) : (jt ? c01 : c00);
#pragma unroll
                for (int r = 0; r < 16; r += 2) {
                    float t0 = C[r], t1 = C[r + 1];
                    // -|t| = t | signbit  (1 op each)
                    float n0 = __uint_as_float(__float_as_uint(t0) | 0x80000000u);
                    float n1 = __uint_as_float(__float_as_uint(t1) | 0x80000000u);
                    f32x2 s2; s2[0] = n0 * 8388608.0f; s2[1] = n1 * 8388608.0f;
                    float u0 = __int_as_float((int)s2[0] + SCH_BITS);  // ~2^{-|t0|}
                    float u1 = __int_as_float((int)s2[1] + SCH_BITS);
                    bool  m0 = (trow[r] == tc), m1 = (trow[r + 1] == tc);
                    f32x2 u2;  u2[0] = u0;           u2[1] = u1;
                    f32x2 um;  um[0] = m0 ? u0 : 0.f; um[1] = m1 ? u1 : 0.f;
                    prodA = prodA + prodA * u2;      // v_pk_fma: prod *= (1+u)
                    prodS = prodS + prodS * um;
                    f32x2 rl;  rl[0] = fmaxf(t0, 0.f); rl[1] = fmaxf(t1, 0.f);
                    sRelu = sRelu + rl;
                    f32x2 rm;  rm[0] = m0 ? rl[0] : 0.f; rm[1] = m1 ? rl[1] : 0.f;
                    sReluS = sReluS + rm;
                    f32x2 tm;  tm[0] = m0 ? t0 : 0.f; tm[1] = m1 ? t1 : 0.f;
                    tSum = tSum + tm;
                }
            }
        }
    } else {
#pragma unroll
        for (int it = 0; it < 2; ++it) {
            int trow[16], lrr[16];
#pragma unroll
            for (int r = 0; r < 16; ++r) {
                lrr[r] = wr * 64 + it * 32 + (r & 3) + 8 * (r >> 2) + 4 * hi;
                trow[r] = tI[lrr[r]];
            }
#pragma unroll
            for (int jt = 0; jt < 2; ++jt) {
                const int lc = wc * 64 + jt * 32 + lrow;
                const int tc = tJ[lc];
                const f32x16& C = it ? (jt ? c11 : c10) : (jt ? c01 : c00);
#pragma unroll
                for (int r = 0; r < 16; r += 2) {
                    float t0 = C[r], t1 = C[r + 1];
                    float n0 = __uint_as_float(__float_as_uint(t0) | 0x80000000u);
                    float n1 = __uint_as_float(__float_as_uint(t1) | 0x80000000u);
                    f32x2 s2; s2[0] = n0 * 8388608.0f; s2[1] = n1 * 8388608.0f;
                    float u0 = __int_as_float((int)s2[0] + SCH_BITS);
                    float u1 = __int_as_float((int)s2[1] + SCH_BITS);
                    bool  v0 = lc > lrr[r],        v1 = lc > lrr[r + 1];
                    bool  m0 = v0 && (trow[r] == tc), m1 = v1 && (trow[r + 1] == tc);
                    f32x2 uv;  uv[0] = v0 ? u0 : 0.f; uv[1] = v1 ? u1 : 0.f;
                    f32x2 um;  um[0] = m0 ? u0 : 0.f; um[1] = m1 ? u1 : 0.f;
                    prodA = prodA + prodA * uv;
                    prodS = prodS + prodS * um;
                    f32x2 rl;  rl[0] = fmaxf(t0, 0.f); rl[1] = fmaxf(t1, 0.f);
                    f32x2 rv;  rv[0] = v0 ? rl[0] : 0.f; rv[1] = v1 ? rl[1] : 0.f;
                    sRelu = sRelu + rv;
                    f32x2 rm;  rm[0] = m0 ? rl[0] : 0.f; rm[1] = m1 ? rl[1] : 0.f;
                    sReluS = sReluS + rm;
                    f32x2 tm;  tm[0] = m0 ? t0 : 0.f; tm[1] = m1 ? t1 : 0.f;
                    tSum = tSum + tm;
                }
            }
        }
    }

    float s_all  = (sRelu[0]  + sRelu[1])  + flog2(prodA[0] * prodA[1]);
    float s_same = (sReluS[0] + sReluS[1]) + flog2(prodS[0] * prodS[1]);
    float t_same = tSum[0] + tSum[1];

#pragma unroll
    for (int d = 32; d > 0; d >>= 1) {
        s_all  += __shfl_xor(s_all,  d, 64);
        s_same += __shfl_xor(s_same, d, 64);
        t_same += __shfl_xor(t_same, d, 64);
    }
    if (lane == 0) { red[wave] = s_all; red[4 + wave] = s_same; red[8 + wave] = t_same; }

    {   // cls softmax on preloaded registers
        float nll = 0.f;
        if (crow < NPTS) {
            float m = fmaxf(cx1, cx2);
#pragma unroll
            for (int d = 32; d > 0; d >>= 1) m = fmaxf(m, __shfl_xor(m, d, 64));
            float e = __expf(cx1 - m) + ((lane + 64 < NCLS) ? __expf(cx2 - m) : 0.f);
#pragma unroll
            for (int d = 32; d > 0; d >>= 1) e += __shfl_xor(e, d, 64);
            if (lane == 0) nll = m + __logf(e) - cxt;
        }
        if (lane == 0) red[12 + wave] = nll;
    }
    __syncthreads();
    if (tid == 0) {
        ws[p]              = (double)red[0]  + (double)red[1]  + (double)red[2]  + (double)red[3];
        ws[NPAIRS + p]     = (double)red[4]  + (double)red[5]  + (double)red[6]  + (double)red[7];
        ws[2 * NPAIRS + p] = (double)red[8]  + (double)red[9]  + (double)red[10] + (double)red[11];
        ws[WS_CLS + p]     = (double)red[12] + (double)red[13] + (double)red[14] + (double)red[15];
    }
}

// ---------------------------------------------------------------------------
// Finalize: histogram -> S0/S1 weights; double reduction; ln2 fold here.
// ---------------------------------------------------------------------------
__global__ __launch_bounds__(256) void final_kernel(const int* __restrict__ tgt,
                                                    const double* __restrict__ ws,
                                                    float* __restrict__ out) {
    __shared__ int hist[NCLS];
    __shared__ double r0[256], r1[256], r2[256], rc[256];
    const int tid = threadIdx.x;

    for (int i = tid; i < NCLS; i += 256) hist[i] = 0;
    __syncthreads();
    for (int i = tid; i < NPTS; i += 256) atomicAdd(&hist[tgt[i]], 1);
    __syncthreads();

    double a = 0.0, s = 0.0, t = 0.0, c = 0.0;
    for (int i = tid; i < NPAIRS; i += 256) {
        a += ws[i];
        s += ws[NPAIRS + i];
        t += ws[2 * NPAIRS + i];
        c += ws[WS_CLS + i];
    }
    r0[tid] = a; r1[tid] = s; r2[tid] = t; rc[tid] = c;
    __syncthreads();
    for (int sdt = 128; sdt > 0; sdt >>= 1) {
        if (tid < sdt) {
            r0[tid] += r0[tid + sdt];
            r1[tid] += r1[tid + sdt];
            r2[tid] += r2[tid + sdt];
            rc[tid] += rc[tid + sdt];
        }
        __syncthreads();
    }

    if (tid == 0) {
        double n_pos = 0.0;
        for (int k = 0; k < NCLS; k++) {
            double cc = (double)hist[k];
            n_pos += cc * cc;
        }
        const double Nd = (double)NPTS;
        double S1 = n_pos - Nd;
        double S0 = Nd * Nd - n_pos;
        if (S0 == 0.0) S0 = 1.0;
        if (S1 == 0.0) S1 = 1.0;
        const double S = S0 + S1;
        // partials in log2 / log2e units -> single ln2 factor here
        const double sum_lower =
            ((S / S0) * (r0[0] - r1[0]) + (S / S1) * (r1[0] - r2[0])) * LN2;
        const double count = Nd * (Nd - 1.0) * 0.5;
        const double hash_loss = sum_lower / count;
        const double cls_loss  = rc[0] / Nd;
        const double loss = 1.0 * cls_loss + 0.01 * hash_loss;
        out[0] = (float)hash_loss;
        out[1] = (float)cls_loss;
        out[2] = (float)loss;
    }
}

// ---------------------------------------------------------------------------
extern "C" void kernel_launch(void* const* d_in, const int* in_sizes, int n_in,
                              void* d_out, int out_size, void* d_ws, size_t ws_size,
                              hipStream_t stream) {
    const float* H   = (const float*)d_in[0];
    const float* X   = (const float*)d_in[1];
    const int*   tgt = (const int*)d_in[2];
    float* out = (float*)d_out;
    double* wsd = (double*)d_ws;

    hash_cls_kernel<<<NPAIRS, 256, 0, stream>>>(H, X, tgt, wsd);
    final_kernel<<<1, 256, 0, stream>>>(tgt, wsd, out);
}